// Round 1
// baseline (2205.525 us; speedup 1.0000x reference)
//
#include <hip/hip_runtime.h>

// GCN 2-layer: out = A_hat @ relu(A_hat @ (X W1) + b1) W2 + b2
// A_hat = D^-1/2 (A + I) D^-1/2, deg counted at dst (in-degree incl self-loop).
//
// Decomposition per layer:
//   hh   = diag(dinv) * (X @ W)              (row-scaled GEMM)
//   agg  = hh (self loop) + scatter-add over edges: agg[dst] += hh[src]
//   out  = act(diag(dinv) * agg + b)

#define CIN 256
#define CHID 128
#define COUT 64

// ---------- degree ----------
__global__ void k_fill1(float* __restrict__ p, int n) {
  int i = blockIdx.x * blockDim.x + threadIdx.x;
  if (i < n) p[i] = 1.0f;  // self-loop
}

__global__ void k_count(const int* __restrict__ dst, float* __restrict__ deg, int e) {
  int i = blockIdx.x * blockDim.x + threadIdx.x;
  if (i < e) atomicAdd(&deg[dst[i]], 1.0f);
}

__global__ void k_rsqrt(float* __restrict__ p, int n) {
  int i = blockIdx.x * blockDim.x + threadIdx.x;
  if (i < n) p[i] = rsqrtf(p[i]);
}

// ---------- row-scaled GEMM: out[r][c] = dinv[r] * sum_k X[r][k] W[k][c] ----------
// 256 threads/block, R rows per block staged in LDS. G=256/C row groups,
// each thread accumulates RPT=R/G rows for one channel c.
template <int K, int C, int R>
__global__ __launch_bounds__(256) void k_gemm_rowscale(
    const float* __restrict__ X, const float* __restrict__ W,
    const float* __restrict__ dinv, float* __restrict__ out) {
  __shared__ float xs[R][K + 4];
  const int tid = threadIdx.x;
  const int row0 = blockIdx.x * R;
  const int K4 = K / 4;

  // cooperative load of R rows of X (coalesced float4)
  for (int i = tid; i < R * K4; i += 256) {
    int r = i / K4, kk = i - r * K4;
    *(float4*)&xs[r][kk * 4] =
        *(const float4*)(X + (size_t)(row0 + r) * K + (size_t)kk * 4);
  }
  __syncthreads();

  const int c = tid % C;
  const int g = tid / C;
  const int G = 256 / C;
  const int RPT = R / G;

  float acc[RPT];
#pragma unroll
  for (int r = 0; r < RPT; ++r) acc[r] = 0.0f;

  for (int k = 0; k < K; k += 4) {
    float w0 = W[(size_t)(k + 0) * C + c];
    float w1 = W[(size_t)(k + 1) * C + c];
    float w2 = W[(size_t)(k + 2) * C + c];
    float w3 = W[(size_t)(k + 3) * C + c];
#pragma unroll
    for (int r = 0; r < RPT; ++r) {
      float4 x4 = *(const float4*)&xs[g * RPT + r][k];
      acc[r] = fmaf(x4.x, w0, acc[r]);
      acc[r] = fmaf(x4.y, w1, acc[r]);
      acc[r] = fmaf(x4.z, w2, acc[r]);
      acc[r] = fmaf(x4.w, w3, acc[r]);
    }
  }

#pragma unroll
  for (int r = 0; r < RPT; ++r) {
    int row = row0 + g * RPT + r;
    out[(size_t)row * C + c] = dinv[row] * acc[r];
  }
}

// ---------- float4 copy (self-loop init) ----------
__global__ void k_copy4(const float4* __restrict__ a, float4* __restrict__ b, int n4) {
  int i = blockIdx.x * blockDim.x + threadIdx.x;
  int stride = gridDim.x * blockDim.x;
  for (; i < n4; i += stride) b[i] = a[i];
}

// ---------- edge scatter-add: agg[dst] += hh[src] ----------
template <int C>
__global__ __launch_bounds__(256) void k_scatter(
    const int* __restrict__ src, const int* __restrict__ dst,
    const float* __restrict__ h, float* __restrict__ agg, int e) {
  const int Q = C / 4;  // float4 chunks per edge
  long long gi = (long long)blockIdx.x * blockDim.x + threadIdx.x;
  if (gi >= (long long)e * Q) return;
  int ei = (int)(gi / Q);
  int q = (int)(gi - (long long)ei * Q);
  int s = src[ei], d = dst[ei];
  float4 v = *(const float4*)&h[(size_t)s * C + (size_t)q * 4];
  float* o = &agg[(size_t)d * C + (size_t)q * 4];
  atomicAdd(o + 0, v.x);
  atomicAdd(o + 1, v.y);
  atomicAdd(o + 2, v.z);
  atomicAdd(o + 3, v.w);
}

// ---------- post: out = act(dinv[row]*agg + b[c]) ----------
template <int C, bool RELU>
__global__ void k_post(const float* __restrict__ agg, const float* __restrict__ dinv,
                       const float* __restrict__ bias, float* __restrict__ out,
                       int total) {
  int i = blockIdx.x * blockDim.x + threadIdx.x;
  if (i >= total) return;
  int row = i / C;
  int c = i - row * C;
  float v = dinv[row] * agg[i] + bias[c];
  if (RELU) v = fmaxf(v, 0.0f);
  out[i] = v;
}

extern "C" void kernel_launch(void* const* d_in, const int* in_sizes, int n_in,
                              void* d_out, int out_size, void* d_ws, size_t ws_size,
                              hipStream_t stream) {
  const float* x   = (const float*)d_in[0];
  const int*   ei  = (const int*)d_in[1];
  const float* W1  = (const float*)d_in[2];
  const float* b1  = (const float*)d_in[3];
  const float* W2  = (const float*)d_in[4];
  const float* b2  = (const float*)d_in[5];
  float* out = (float*)d_out;

  const int n = in_sizes[0] / CIN;   // 50000
  const int e = in_sizes[1] / 2;     // 800000
  const int* src = ei;
  const int* dst = ei + e;

  // workspace layout
  char* ws = (char*)d_ws;
  float* dinv = (float*)ws;                       // n floats
  float* hh   = (float*)(ws + (1 << 18));         // n*CHID floats (25.6 MB)
  float* agg  = (float*)(ws + (1 << 18) + (size_t)n * CHID * sizeof(float));

  const int B = 256;

  // --- degree / dinv ---
  k_fill1<<<(n + B - 1) / B, B, 0, stream>>>(dinv, n);
  k_count<<<(e + B - 1) / B, B, 0, stream>>>(dst, dinv, e);
  k_rsqrt<<<(n + B - 1) / B, B, 0, stream>>>(dinv, n);

  // --- layer 1: hh = rowscale(x @ W1) ---
  k_gemm_rowscale<CIN, CHID, 16><<<n / 16, 256, 0, stream>>>(x, W1, dinv, hh);
  // agg = hh (self loop)
  k_copy4<<<2048, B, 0, stream>>>((const float4*)hh, (float4*)agg, n * CHID / 4);
  // agg[dst] += hh[src]
  {
    long long total = (long long)e * (CHID / 4);
    int blocks = (int)((total + B - 1) / B);
    k_scatter<CHID><<<blocks, B, 0, stream>>>(src, dst, hh, agg, e);
  }
  // hh = relu(dinv*agg + b1)   (reuse hh buffer as layer-2 input)
  k_post<CHID, true><<<(n * CHID + B - 1) / B, B, 0, stream>>>(agg, dinv, b1, hh, n * CHID);

  // --- layer 2: agg(buf) = rowscale(hh @ W2) ---
  k_gemm_rowscale<CHID, COUT, 16><<<n / 16, 256, 0, stream>>>(hh, W2, dinv, agg);
  // out = hh2 (self loop)
  k_copy4<<<2048, B, 0, stream>>>((const float4*)agg, (float4*)out, n * COUT / 4);
  {
    long long total = (long long)e * (COUT / 4);
    int blocks = (int)((total + B - 1) / B);
    k_scatter<COUT><<<blocks, B, 0, stream>>>(src, dst, agg, out, e);
  }
  // out = dinv*out + b2 (in place, no relu)
  k_post<COUT, false><<<(n * COUT + B - 1) / B, B, 0, stream>>>(out, dinv, b2, out, n * COUT);
}

// Round 2
// 290.325 us; speedup vs baseline: 7.5968x; 7.5968x over previous
//
#include <hip/hip_runtime.h>

// GCN 2-layer: out = A_hat @ relu(A_hat @ (X W1) + b1) W2 + b2
// A_hat = D^-1/2 (A + I) D^-1/2.
//
// R2: CSR-by-dst gather aggregation (replaces 154M float atomics with
// coalesced row gathers of an L3-resident buffer).
//
// Per layer:
//   hh   = diag(dinv) * (X @ W)             (row-scaled GEMM)
//   out  = act(dinv[j] * (hh[j] + sum_{e: dst=j} hh[src[e]]) + b)

#define CIN 256
#define CHID 128
#define COUT 64
#define SCAN_B 256

// ---------- small utils ----------
__global__ void k_zero_int(int* __restrict__ p, int n) {
  int i = blockIdx.x * blockDim.x + threadIdx.x;
  if (i < n) p[i] = 0;
}

__global__ void k_count_int(const int* __restrict__ dst, int* __restrict__ deg, int e) {
  int i = blockIdx.x * blockDim.x + threadIdx.x;
  if (i < e) atomicAdd(&deg[dst[i]], 1);
}

// ---------- 3-kernel exclusive scan over deg (n <= 65536 => nb <= 256) ----------
__global__ void k_scan1(const int* __restrict__ deg, int* __restrict__ incl,
                        int* __restrict__ bsum, int n) {
  __shared__ int s[SCAN_B];
  int i = blockIdx.x * SCAN_B + threadIdx.x;
  int v = (i < n) ? deg[i] : 0;
  s[threadIdx.x] = v;
  __syncthreads();
  for (int off = 1; off < SCAN_B; off <<= 1) {
    int t = (threadIdx.x >= off) ? s[threadIdx.x - off] : 0;
    __syncthreads();
    s[threadIdx.x] += t;
    __syncthreads();
  }
  if (i < n) incl[i] = s[threadIdx.x];
  if (threadIdx.x == SCAN_B - 1) bsum[blockIdx.x] = s[SCAN_B - 1];
}

__global__ void k_scan2(int* __restrict__ bsum, int nb) {
  __shared__ int s[SCAN_B];
  int v = (threadIdx.x < nb) ? bsum[threadIdx.x] : 0;
  s[threadIdx.x] = v;
  __syncthreads();
  for (int off = 1; off < SCAN_B; off <<= 1) {
    int t = (threadIdx.x >= off) ? s[threadIdx.x - off] : 0;
    __syncthreads();
    s[threadIdx.x] += t;
    __syncthreads();
  }
  if (threadIdx.x < nb) bsum[threadIdx.x] = (threadIdx.x == 0) ? 0 : s[threadIdx.x - 1];
}

// rowptr[i+1] = excl_base + incl[i]; counters[i] = rowptr[i]; dinv[i] = rsqrt(deg+1)
__global__ void k_scan3(const int* __restrict__ incl, const int* __restrict__ bsum,
                        const int* __restrict__ deg, int* __restrict__ rowptr,
                        int* __restrict__ counters, float* __restrict__ dinv, int n) {
  int i = blockIdx.x * SCAN_B + threadIdx.x;
  if (i >= n) return;
  int v = bsum[blockIdx.x] + incl[i];
  rowptr[i + 1] = v;
  counters[i] = v - deg[i];
  if (i == 0) rowptr[0] = 0;
  dinv[i] = rsqrtf((float)(deg[i] + 1));  // +1 self-loop
}

__global__ void k_fill_csr(const int* __restrict__ src, const int* __restrict__ dst,
                           int* __restrict__ counters, int* __restrict__ csr, int e) {
  int i = blockIdx.x * blockDim.x + threadIdx.x;
  if (i >= e) return;
  int slot = atomicAdd(&counters[dst[i]], 1);
  csr[slot] = src[i];
}

// ---------- row-scaled GEMM: out[r][c] = dinv[r] * sum_k X[r][k] W[k][c] ----------
template <int K, int C, int R>
__global__ __launch_bounds__(256) void k_gemm_rowscale(
    const float* __restrict__ X, const float* __restrict__ W,
    const float* __restrict__ dinv, float* __restrict__ out) {
  __shared__ float xs[R][K + 4];
  const int tid = threadIdx.x;
  const int row0 = blockIdx.x * R;
  const int K4 = K / 4;

  for (int i = tid; i < R * K4; i += 256) {
    int r = i / K4, kk = i - r * K4;
    *(float4*)&xs[r][kk * 4] =
        *(const float4*)(X + (size_t)(row0 + r) * K + (size_t)kk * 4);
  }
  __syncthreads();

  const int c = tid % C;
  const int g = tid / C;
  const int G = 256 / C;
  const int RPT = R / G;

  float acc[RPT];
#pragma unroll
  for (int r = 0; r < RPT; ++r) acc[r] = 0.0f;

  for (int k = 0; k < K; k += 4) {
    float w0 = W[(size_t)(k + 0) * C + c];
    float w1 = W[(size_t)(k + 1) * C + c];
    float w2 = W[(size_t)(k + 2) * C + c];
    float w3 = W[(size_t)(k + 3) * C + c];
#pragma unroll
    for (int r = 0; r < RPT; ++r) {
      float4 x4 = *(const float4*)&xs[g * RPT + r][k];
      acc[r] = fmaf(x4.x, w0, acc[r]);
      acc[r] = fmaf(x4.y, w1, acc[r]);
      acc[r] = fmaf(x4.z, w2, acc[r]);
      acc[r] = fmaf(x4.w, w3, acc[r]);
    }
  }

#pragma unroll
  for (int r = 0; r < RPT; ++r) {
    int row = row0 + g * RPT + r;
    out[(size_t)row * C + c] = dinv[row] * acc[r];
  }
}

// ---------- gather aggregation: out[j] = act(dinv[j]*(hh[j] + sum hh[csr]) + b) ----------
// C/4 lanes per node (float4 per lane), 256 threads/block.
template <int C, bool RELU>
__global__ __launch_bounds__(256) void k_agg(
    const float* __restrict__ hh, const int* __restrict__ rowptr,
    const int* __restrict__ csr, const float* __restrict__ dinv,
    const float* __restrict__ bias, float* __restrict__ out, int n) {
  const int LPN = C / 4;        // lanes per node
  const int NPB = 256 / LPN;    // nodes per block
  const int tid = threadIdx.x;
  const int node = blockIdx.x * NPB + tid / LPN;
  const int q = tid % LPN;
  if (node >= n) return;

  float4 acc = *(const float4*)&hh[(size_t)node * C + (size_t)q * 4];  // self-loop
  const int beg = rowptr[node];
  const int end = rowptr[node + 1];
  for (int k = beg; k < end; ++k) {
    int s = csr[k];
    float4 v = *(const float4*)&hh[(size_t)s * C + (size_t)q * 4];
    acc.x += v.x; acc.y += v.y; acc.z += v.z; acc.w += v.w;
  }
  const float dn = dinv[node];
  float4 b4 = *(const float4*)&bias[q * 4];
  float4 r;
  r.x = dn * acc.x + b4.x;
  r.y = dn * acc.y + b4.y;
  r.z = dn * acc.z + b4.z;
  r.w = dn * acc.w + b4.w;
  if (RELU) {
    r.x = fmaxf(r.x, 0.0f); r.y = fmaxf(r.y, 0.0f);
    r.z = fmaxf(r.z, 0.0f); r.w = fmaxf(r.w, 0.0f);
  }
  *(float4*)&out[(size_t)node * C + (size_t)q * 4] = r;
}

extern "C" void kernel_launch(void* const* d_in, const int* in_sizes, int n_in,
                              void* d_out, int out_size, void* d_ws, size_t ws_size,
                              hipStream_t stream) {
  const float* x  = (const float*)d_in[0];
  const int*   ei = (const int*)d_in[1];
  const float* W1 = (const float*)d_in[2];
  const float* b1 = (const float*)d_in[3];
  const float* W2 = (const float*)d_in[4];
  const float* b2 = (const float*)d_in[5];
  float* out = (float*)d_out;

  const int n = in_sizes[0] / CIN;  // 50000
  const int e = in_sizes[1] / 2;    // 800000
  const int* src = ei;
  const int* dst = ei + e;

  // workspace layout (aligned 256B)
  size_t off = 0;
  auto alloc = [&](size_t bytes) {
    size_t o = off;
    off = (off + bytes + 255) & ~(size_t)255;
    return o;
  };
  char* ws = (char*)d_ws;
  int*   degi     = (int*)(ws + alloc((size_t)n * 4));
  int*   incl     = (int*)(ws + alloc((size_t)n * 4));
  int*   bsum     = (int*)(ws + alloc((size_t)SCAN_B * 4));
  int*   rowptr   = (int*)(ws + alloc((size_t)(n + 1) * 4));
  int*   counters = (int*)(ws + alloc((size_t)n * 4));
  int*   csr      = (int*)(ws + alloc((size_t)e * 4));
  float* dinv     = (float*)(ws + alloc((size_t)n * 4));
  float* bufA     = (float*)(ws + alloc((size_t)n * CHID * 4));
  float* bufB     = (float*)(ws + alloc((size_t)n * CHID * 4));

  const int B = 256;
  const int nb = (n + SCAN_B - 1) / SCAN_B;

  // --- CSR build + dinv ---
  k_zero_int<<<(n + B - 1) / B, B, 0, stream>>>(degi, n);
  k_count_int<<<(e + B - 1) / B, B, 0, stream>>>(dst, degi, e);
  k_scan1<<<nb, SCAN_B, 0, stream>>>(degi, incl, bsum, n);
  k_scan2<<<1, SCAN_B, 0, stream>>>(bsum, nb);
  k_scan3<<<nb, SCAN_B, 0, stream>>>(incl, bsum, degi, rowptr, counters, dinv, n);
  k_fill_csr<<<(e + B - 1) / B, B, 0, stream>>>(src, dst, counters, csr, e);

  // --- layer 1 ---
  k_gemm_rowscale<CIN, CHID, 16><<<n / 16, 256, 0, stream>>>(x, W1, dinv, bufA);
  {
    const int NPB = 256 / (CHID / 4);  // 8 nodes/block
    k_agg<CHID, true><<<(n + NPB - 1) / NPB, 256, 0, stream>>>(
        bufA, rowptr, csr, dinv, b1, bufB, n);
  }

  // --- layer 2 ---
  k_gemm_rowscale<CHID, COUT, 16><<<n / 16, 256, 0, stream>>>(bufB, W2, dinv, bufA);
  {
    const int NPB = 256 / (COUT / 4);  // 16 nodes/block
    k_agg<COUT, false><<<(n + NPB - 1) / NPB, 256, 0, stream>>>(
        bufA, rowptr, csr, dinv, b2, out, n);
  }
}

// Round 3
// 282.874 us; speedup vs baseline: 7.7968x; 1.0263x over previous
//
#include <hip/hip_runtime.h>

// GCN 2-layer: out = A_hat @ relu(A_hat @ (X W1) + b1) W2 + b2
// A_hat = D^-1/2 (A + I) D^-1/2.
//
// R3: register-tiled fp32 GEMM (8x4 / 4x4 outputs per thread, both operands
// staged in LDS, transposed X tile, prefetch-to-regs across the barrier).
// CSR gather aggregation unchanged from R2.

#define CIN 256
#define CHID 128
#define COUT 64
#define SCAN_B 256

// ---------- small utils ----------
__global__ void k_zero_int(int* __restrict__ p, int n) {
  int i = blockIdx.x * blockDim.x + threadIdx.x;
  if (i < n) p[i] = 0;
}

__global__ void k_count_int(const int* __restrict__ dst, int* __restrict__ deg, int e) {
  int i = blockIdx.x * blockDim.x + threadIdx.x;
  if (i < e) atomicAdd(&deg[dst[i]], 1);
}

// ---------- 3-kernel exclusive scan over deg (n <= 65536 => nb <= 256) ----------
__global__ void k_scan1(const int* __restrict__ deg, int* __restrict__ incl,
                        int* __restrict__ bsum, int n) {
  __shared__ int s[SCAN_B];
  int i = blockIdx.x * SCAN_B + threadIdx.x;
  int v = (i < n) ? deg[i] : 0;
  s[threadIdx.x] = v;
  __syncthreads();
  for (int off = 1; off < SCAN_B; off <<= 1) {
    int t = (threadIdx.x >= off) ? s[threadIdx.x - off] : 0;
    __syncthreads();
    s[threadIdx.x] += t;
    __syncthreads();
  }
  if (i < n) incl[i] = s[threadIdx.x];
  if (threadIdx.x == SCAN_B - 1) bsum[blockIdx.x] = s[SCAN_B - 1];
}

__global__ void k_scan2(int* __restrict__ bsum, int nb) {
  __shared__ int s[SCAN_B];
  int v = (threadIdx.x < nb) ? bsum[threadIdx.x] : 0;
  s[threadIdx.x] = v;
  __syncthreads();
  for (int off = 1; off < SCAN_B; off <<= 1) {
    int t = (threadIdx.x >= off) ? s[threadIdx.x - off] : 0;
    __syncthreads();
    s[threadIdx.x] += t;
    __syncthreads();
  }
  if (threadIdx.x < nb) bsum[threadIdx.x] = (threadIdx.x == 0) ? 0 : s[threadIdx.x - 1];
}

// rowptr[i+1] = excl_base + incl[i]; counters[i] = rowptr[i]; dinv[i] = rsqrt(deg+1)
__global__ void k_scan3(const int* __restrict__ incl, const int* __restrict__ bsum,
                        const int* __restrict__ deg, int* __restrict__ rowptr,
                        int* __restrict__ counters, float* __restrict__ dinv, int n) {
  int i = blockIdx.x * SCAN_B + threadIdx.x;
  if (i >= n) return;
  int v = bsum[blockIdx.x] + incl[i];
  rowptr[i + 1] = v;
  counters[i] = v - deg[i];
  if (i == 0) rowptr[0] = 0;
  dinv[i] = rsqrtf((float)(deg[i] + 1));  // +1 self-loop
}

__global__ void k_fill_csr(const int* __restrict__ src, const int* __restrict__ dst,
                           int* __restrict__ counters, int* __restrict__ csr, int e) {
  int i = blockIdx.x * blockDim.x + threadIdx.x;
  if (i >= e) return;
  int slot = atomicAdd(&counters[dst[i]], 1);
  csr[slot] = src[i];
}

// ---------- register-tiled row-scaled GEMM ----------
// out[r][c] = dinv[r] * sum_k X[r][k] W[k][c]
// 256 threads; tile = TM rows x C cols; thread tile = RPT rows x 4 cols.
// xs stored transposed xs[k][row] (pad 68: write conflicts 2-way = free,
// reads are 16/32-lane broadcasts). ws[k][C] row-major.
template <int K, int C, int TM>
__global__ __launch_bounds__(256) void k_gemm2(
    const float* __restrict__ X, const float* __restrict__ W,
    const float* __restrict__ dinv, float* __restrict__ out, int M) {
  constexpr int KB = 16;
  constexpr int TCOLS = C / 4;        // threads along N
  constexpr int TROWS = 256 / TCOLS;  // thread rows
  constexpr int RPT = TM / TROWS;     // rows per thread (8 or 4)
  constexpr int XPAD = 68;
  constexpr int WF4 = (KB * C) / 1024;  // W float4 loads per thread per chunk

  __shared__ float xs[KB][XPAD];
  __shared__ float ws[KB][C];

  const int tid = threadIdx.x;
  const int row0 = blockIdx.x * TM;
  const int tcol = tid % TCOLS;
  const int trow = tid / TCOLS;

  // staging assignment: X tile = TM*KB = 1024 floats -> 1 float4/thread
  const int xr = tid / (KB / 4);        // tile row 0..TM-1
  const int xk = (tid % (KB / 4)) * 4;  // k offset within chunk
  int gxrow = row0 + xr;
  if (gxrow >= M) gxrow = M - 1;  // clamp (dup loads, outputs guarded)

  float4 xreg;
  float4 wreg[WF4];

  auto load_chunk = [&](int k0) {
    xreg = *(const float4*)(X + (size_t)gxrow * K + k0 + xk);
#pragma unroll
    for (int i = 0; i < WF4; ++i) {
      int idx = tid + i * 256;  // float4 index within KBxC chunk
      wreg[i] = *(const float4*)(W + (size_t)(k0 + idx / TCOLS) * C +
                                 (size_t)(idx % TCOLS) * 4);
    }
  };
  auto write_lds = [&]() {
    xs[xk + 0][xr] = xreg.x;
    xs[xk + 1][xr] = xreg.y;
    xs[xk + 2][xr] = xreg.z;
    xs[xk + 3][xr] = xreg.w;
#pragma unroll
    for (int i = 0; i < WF4; ++i) {
      int idx = tid + i * 256;
      *(float4*)&ws[idx / TCOLS][(idx % TCOLS) * 4] = wreg[i];
    }
  };

  float acc[RPT][4];
#pragma unroll
  for (int r = 0; r < RPT; ++r)
#pragma unroll
    for (int j = 0; j < 4; ++j) acc[r][j] = 0.0f;

  constexpr int NCH = K / KB;
  load_chunk(0);
#pragma unroll 1
  for (int ch = 0; ch < NCH; ++ch) {
    __syncthreads();  // previous compute done reading LDS
    write_lds();
    __syncthreads();
    if (ch + 1 < NCH) load_chunk((ch + 1) * KB);  // hide HBM under compute
#pragma unroll
    for (int k = 0; k < KB; ++k) {
      float4 w4 = *(const float4*)&ws[k][tcol * 4];
      float xv[RPT];
#pragma unroll
      for (int rr = 0; rr < RPT; rr += 4) {
        float4 x4 = *(const float4*)&xs[k][trow * RPT + rr];
        xv[rr + 0] = x4.x;
        xv[rr + 1] = x4.y;
        xv[rr + 2] = x4.z;
        xv[rr + 3] = x4.w;
      }
#pragma unroll
      for (int r = 0; r < RPT; ++r) {
        acc[r][0] = fmaf(xv[r], w4.x, acc[r][0]);
        acc[r][1] = fmaf(xv[r], w4.y, acc[r][1]);
        acc[r][2] = fmaf(xv[r], w4.z, acc[r][2]);
        acc[r][3] = fmaf(xv[r], w4.w, acc[r][3]);
      }
    }
  }

#pragma unroll
  for (int r = 0; r < RPT; ++r) {
    int row = row0 + trow * RPT + r;
    if (row < M) {
      float dn = dinv[row];
      float4 o;
      o.x = dn * acc[r][0];
      o.y = dn * acc[r][1];
      o.z = dn * acc[r][2];
      o.w = dn * acc[r][3];
      *(float4*)(out + (size_t)row * C + (size_t)tcol * 4) = o;
    }
  }
}

// ---------- gather aggregation: out[j] = act(dinv[j]*(hh[j] + sum hh[csr]) + b) ----------
template <int C, bool RELU>
__global__ __launch_bounds__(256) void k_agg(
    const float* __restrict__ hh, const int* __restrict__ rowptr,
    const int* __restrict__ csr, const float* __restrict__ dinv,
    const float* __restrict__ bias, float* __restrict__ out, int n) {
  const int LPN = C / 4;      // lanes per node
  const int NPB = 256 / LPN;  // nodes per block
  const int tid = threadIdx.x;
  const int node = blockIdx.x * NPB + tid / LPN;
  const int q = tid % LPN;
  if (node >= n) return;

  float4 acc = *(const float4*)&hh[(size_t)node * C + (size_t)q * 4];  // self-loop
  const int beg = rowptr[node];
  const int end = rowptr[node + 1];
  for (int k = beg; k < end; ++k) {
    int s = csr[k];
    float4 v = *(const float4*)&hh[(size_t)s * C + (size_t)q * 4];
    acc.x += v.x; acc.y += v.y; acc.z += v.z; acc.w += v.w;
  }
  const float dn = dinv[node];
  float4 b4 = *(const float4*)&bias[q * 4];
  float4 r;
  r.x = dn * acc.x + b4.x;
  r.y = dn * acc.y + b4.y;
  r.z = dn * acc.z + b4.z;
  r.w = dn * acc.w + b4.w;
  if (RELU) {
    r.x = fmaxf(r.x, 0.0f); r.y = fmaxf(r.y, 0.0f);
    r.z = fmaxf(r.z, 0.0f); r.w = fmaxf(r.w, 0.0f);
  }
  *(float4*)&out[(size_t)node * C + (size_t)q * 4] = r;
}

extern "C" void kernel_launch(void* const* d_in, const int* in_sizes, int n_in,
                              void* d_out, int out_size, void* d_ws, size_t ws_size,
                              hipStream_t stream) {
  const float* x  = (const float*)d_in[0];
  const int*   ei = (const int*)d_in[1];
  const float* W1 = (const float*)d_in[2];
  const float* b1 = (const float*)d_in[3];
  const float* W2 = (const float*)d_in[4];
  const float* b2 = (const float*)d_in[5];
  float* out = (float*)d_out;

  const int n = in_sizes[0] / CIN;  // 50000
  const int e = in_sizes[1] / 2;    // 800000
  const int* src = ei;
  const int* dst = ei + e;

  // workspace layout (aligned 256B)
  size_t off = 0;
  auto alloc = [&](size_t bytes) {
    size_t o = off;
    off = (off + bytes + 255) & ~(size_t)255;
    return o;
  };
  char* ws = (char*)d_ws;
  int*   degi     = (int*)(ws + alloc((size_t)n * 4));
  int*   incl     = (int*)(ws + alloc((size_t)n * 4));
  int*   bsum     = (int*)(ws + alloc((size_t)SCAN_B * 4));
  int*   rowptr   = (int*)(ws + alloc((size_t)(n + 1) * 4));
  int*   counters = (int*)(ws + alloc((size_t)n * 4));
  int*   csr      = (int*)(ws + alloc((size_t)e * 4));
  float* dinv     = (float*)(ws + alloc((size_t)n * 4));
  float* bufA     = (float*)(ws + alloc((size_t)n * CHID * 4));
  float* bufB     = (float*)(ws + alloc((size_t)n * CHID * 4));

  const int B = 256;
  const int nb = (n + SCAN_B - 1) / SCAN_B;

  // --- CSR build + dinv ---
  k_zero_int<<<(n + B - 1) / B, B, 0, stream>>>(degi, n);
  k_count_int<<<(e + B - 1) / B, B, 0, stream>>>(dst, degi, e);
  k_scan1<<<nb, SCAN_B, 0, stream>>>(degi, incl, bsum, n);
  k_scan2<<<1, SCAN_B, 0, stream>>>(bsum, nb);
  k_scan3<<<nb, SCAN_B, 0, stream>>>(incl, bsum, degi, rowptr, counters, dinv, n);
  k_fill_csr<<<(e + B - 1) / B, B, 0, stream>>>(src, dst, counters, csr, e);

  // --- layer 1 ---
  k_gemm2<CIN, CHID, 64><<<(n + 63) / 64, 256, 0, stream>>>(x, W1, dinv, bufA, n);
  {
    const int NPB = 256 / (CHID / 4);  // 8 nodes/block
    k_agg<CHID, true><<<(n + NPB - 1) / NPB, 256, 0, stream>>>(
        bufA, rowptr, csr, dinv, b1, bufB, n);
  }

  // --- layer 2 ---
  k_gemm2<CHID, COUT, 64><<<(n + 63) / 64, 256, 0, stream>>>(bufB, W2, dinv, bufA, n);
  {
    const int NPB = 256 / (COUT / 4);  // 16 nodes/block
    k_agg<COUT, false><<<(n + NPB - 1) / NPB, 256, 0, stream>>>(
        bufA, rowptr, csr, dinv, b2, out, n);
  }
}

// Round 4
// 247.837 us; speedup vs baseline: 8.8991x; 1.1414x over previous
//
#include <hip/hip_runtime.h>

// GCN 2-layer: out = A_hat @ relu(A_hat @ (X W1) + b1) W2 + b2
// A_hat = D^-1/2 (A + I) D^-1/2.
//
// R4: all intermediate node features stored as bf16 (halves gather traffic,
// gather working set 25.6 -> 12.8 MB); GEMM TM=32 for layer-1 (2x blocks ->
// 24 waves/CU); fp32 accumulation everywhere (error ~1e-3 << 1e-2 thresh).

#define CIN 256
#define CHID 128
#define COUT 64
#define SCAN_B 256

typedef unsigned short ushort_t;
typedef unsigned int uint_t;

__device__ inline ushort_t f2bf(float f) {  // RNE
  union { float f; uint_t u; } v; v.f = f;
  uint_t r = v.u + 0x7FFFu + ((v.u >> 16) & 1u);
  return (ushort_t)(r >> 16);
}
__device__ inline float bf2f(ushort_t u) {
  union { uint_t u; float f; } v; v.u = ((uint_t)u) << 16;
  return v.f;
}
__device__ inline float bf_lo(uint_t u) {  // low ushort of packed pair
  union { uint_t u; float f; } v; v.u = u << 16;
  return v.f;
}
__device__ inline float bf_hi(uint_t u) {  // high ushort
  union { uint_t u; float f; } v; v.u = u & 0xFFFF0000u;
  return v.f;
}
__device__ inline uint_t pack2(float a, float b) {
  return (uint_t)f2bf(a) | ((uint_t)f2bf(b) << 16);
}

// ---------- small utils ----------
__global__ void k_zero_int(int* __restrict__ p, int n) {
  int i = blockIdx.x * blockDim.x + threadIdx.x;
  if (i < n) p[i] = 0;
}

__global__ void k_count_int(const int* __restrict__ dst, int* __restrict__ deg, int e) {
  int i = blockIdx.x * blockDim.x + threadIdx.x;
  if (i < e) atomicAdd(&deg[dst[i]], 1);
}

// ---------- 3-kernel exclusive scan over deg ----------
__global__ void k_scan1(const int* __restrict__ deg, int* __restrict__ incl,
                        int* __restrict__ bsum, int n) {
  __shared__ int s[SCAN_B];
  int i = blockIdx.x * SCAN_B + threadIdx.x;
  int v = (i < n) ? deg[i] : 0;
  s[threadIdx.x] = v;
  __syncthreads();
  for (int off = 1; off < SCAN_B; off <<= 1) {
    int t = (threadIdx.x >= off) ? s[threadIdx.x - off] : 0;
    __syncthreads();
    s[threadIdx.x] += t;
    __syncthreads();
  }
  if (i < n) incl[i] = s[threadIdx.x];
  if (threadIdx.x == SCAN_B - 1) bsum[blockIdx.x] = s[SCAN_B - 1];
}

__global__ void k_scan2(int* __restrict__ bsum, int nb) {
  __shared__ int s[SCAN_B];
  int v = (threadIdx.x < nb) ? bsum[threadIdx.x] : 0;
  s[threadIdx.x] = v;
  __syncthreads();
  for (int off = 1; off < SCAN_B; off <<= 1) {
    int t = (threadIdx.x >= off) ? s[threadIdx.x - off] : 0;
    __syncthreads();
    s[threadIdx.x] += t;
    __syncthreads();
  }
  if (threadIdx.x < nb) bsum[threadIdx.x] = (threadIdx.x == 0) ? 0 : s[threadIdx.x - 1];
}

__global__ void k_scan3(const int* __restrict__ incl, const int* __restrict__ bsum,
                        const int* __restrict__ deg, int* __restrict__ rowptr,
                        int* __restrict__ counters, float* __restrict__ dinv, int n) {
  int i = blockIdx.x * SCAN_B + threadIdx.x;
  if (i >= n) return;
  int v = bsum[blockIdx.x] + incl[i];
  rowptr[i + 1] = v;
  counters[i] = v - deg[i];
  if (i == 0) rowptr[0] = 0;
  dinv[i] = rsqrtf((float)(deg[i] + 1));  // +1 self-loop
}

__global__ void k_fill_csr(const int* __restrict__ src, const int* __restrict__ dst,
                           int* __restrict__ counters, int* __restrict__ csr, int e) {
  int i = blockIdx.x * blockDim.x + threadIdx.x;
  if (i >= e) return;
  int slot = atomicAdd(&counters[dst[i]], 1);
  csr[slot] = src[i];
}

// ---------- register-tiled row-scaled GEMM, bf16 output ----------
// out[r][c] = bf16( dinv[r] * sum_k X[r][k] W[k][c] )
// X fp32 or bf16 (XBF16). 256 threads; tile TM x C; thread tile RPT x 4.
template <int K, int C, int TM, bool XBF16>
__global__ __launch_bounds__(256) void k_gemm_rs(
    const void* __restrict__ Xv, const float* __restrict__ W,
    const float* __restrict__ dinv, ushort_t* __restrict__ out, int M) {
  constexpr int KB = 16;
  constexpr int TCOLS = C / 4;
  constexpr int TROWS = 256 / TCOLS;
  constexpr int RPT = TM / TROWS;  // must be 4
  constexpr int XPAD = TM + 4;
  constexpr int WF4 = (KB * C) / 1024;
  constexpr int XTHREADS = TM * 4;  // threads staging X (float4/ushort4 each)

  static_assert(RPT == 4, "thread row tile must be 4");

  __shared__ float xs[KB][XPAD];  // transposed: xs[k][row]
  __shared__ float ws[KB][C];

  const float* Xf = (const float*)Xv;
  const ushort_t* Xb = (const ushort_t*)Xv;

  const int tid = threadIdx.x;
  const int row0 = blockIdx.x * TM;
  const int tcol = tid % TCOLS;
  const int trow = tid / TCOLS;

  const int xr = tid / (KB / 4);
  const int xk = (tid % (KB / 4)) * 4;
  int gxrow = row0 + xr;
  if (gxrow >= M) gxrow = M - 1;

  float4 xreg;
  float4 wreg[WF4];

  auto load_chunk = [&](int k0) {
    if (XTHREADS == 256 || tid < XTHREADS) {
      if (XBF16) {
        const ushort_t* p = Xb + (size_t)gxrow * K + k0 + xk;
        ushort4 t = *(const ushort4*)p;
        xreg.x = bf2f(t.x); xreg.y = bf2f(t.y);
        xreg.z = bf2f(t.z); xreg.w = bf2f(t.w);
      } else {
        xreg = *(const float4*)(Xf + (size_t)gxrow * K + k0 + xk);
      }
    }
#pragma unroll
    for (int i = 0; i < WF4; ++i) {
      int idx = tid + i * 256;
      wreg[i] = *(const float4*)(W + (size_t)(k0 + idx / TCOLS) * C +
                                 (size_t)(idx % TCOLS) * 4);
    }
  };
  auto write_lds = [&]() {
    if (XTHREADS == 256 || tid < XTHREADS) {
      xs[xk + 0][xr] = xreg.x;
      xs[xk + 1][xr] = xreg.y;
      xs[xk + 2][xr] = xreg.z;
      xs[xk + 3][xr] = xreg.w;
    }
#pragma unroll
    for (int i = 0; i < WF4; ++i) {
      int idx = tid + i * 256;
      *(float4*)&ws[idx / TCOLS][(idx % TCOLS) * 4] = wreg[i];
    }
  };

  float acc[RPT][4];
#pragma unroll
  for (int r = 0; r < RPT; ++r)
#pragma unroll
    for (int j = 0; j < 4; ++j) acc[r][j] = 0.0f;

  constexpr int NCH = K / KB;
  load_chunk(0);
#pragma unroll 1
  for (int ch = 0; ch < NCH; ++ch) {
    __syncthreads();
    write_lds();
    __syncthreads();
    if (ch + 1 < NCH) load_chunk((ch + 1) * KB);
#pragma unroll
    for (int k = 0; k < KB; ++k) {
      float4 w4 = *(const float4*)&ws[k][tcol * 4];
      float4 x4 = *(const float4*)&xs[k][trow * RPT];
      acc[0][0] = fmaf(x4.x, w4.x, acc[0][0]);
      acc[0][1] = fmaf(x4.x, w4.y, acc[0][1]);
      acc[0][2] = fmaf(x4.x, w4.z, acc[0][2]);
      acc[0][3] = fmaf(x4.x, w4.w, acc[0][3]);
      acc[1][0] = fmaf(x4.y, w4.x, acc[1][0]);
      acc[1][1] = fmaf(x4.y, w4.y, acc[1][1]);
      acc[1][2] = fmaf(x4.y, w4.z, acc[1][2]);
      acc[1][3] = fmaf(x4.y, w4.w, acc[1][3]);
      acc[2][0] = fmaf(x4.z, w4.x, acc[2][0]);
      acc[2][1] = fmaf(x4.z, w4.y, acc[2][1]);
      acc[2][2] = fmaf(x4.z, w4.z, acc[2][2]);
      acc[2][3] = fmaf(x4.z, w4.w, acc[2][3]);
      acc[3][0] = fmaf(x4.w, w4.x, acc[3][0]);
      acc[3][1] = fmaf(x4.w, w4.y, acc[3][1]);
      acc[3][2] = fmaf(x4.w, w4.z, acc[3][2]);
      acc[3][3] = fmaf(x4.w, w4.w, acc[3][3]);
    }
  }

#pragma unroll
  for (int r = 0; r < RPT; ++r) {
    int row = row0 + trow * RPT + r;
    if (row < M) {
      float dn = dinv[row];
      ushort4 o;
      o.x = f2bf(dn * acc[r][0]);
      o.y = f2bf(dn * acc[r][1]);
      o.z = f2bf(dn * acc[r][2]);
      o.w = f2bf(dn * acc[r][3]);
      *(ushort4*)(out + (size_t)row * C + (size_t)tcol * 4) = o;
    }
  }
}

// ---------- bf16 gather aggregation ----------
// out[j] = act(dinv[j]*(hh[j] + sum_{e:dst=j} hh[src]) + b); hh bf16.
// C/8 lanes per node, each lane owns 8 consecutive channels (one uint4 load).
template <int C, bool RELU, bool OUTBF16>
__global__ __launch_bounds__(256) void k_aggb(
    const ushort_t* __restrict__ hh, const int* __restrict__ rowptr,
    const int* __restrict__ csr, const float* __restrict__ dinv,
    const float* __restrict__ bias, void* __restrict__ outp, int n) {
  constexpr int LPN = C / 8;
  constexpr int NPB = 256 / LPN;
  const int tid = threadIdx.x;
  const int node = blockIdx.x * NPB + tid / LPN;
  const int q = tid % LPN;
  if (node >= n) return;

  float acc[8];
  {
    uint4 u = *(const uint4*)&hh[(size_t)node * C + (size_t)q * 8];  // self-loop
    acc[0] = bf_lo(u.x); acc[1] = bf_hi(u.x);
    acc[2] = bf_lo(u.y); acc[3] = bf_hi(u.y);
    acc[4] = bf_lo(u.z); acc[5] = bf_hi(u.z);
    acc[6] = bf_lo(u.w); acc[7] = bf_hi(u.w);
  }
  const int beg = rowptr[node];
  const int end = rowptr[node + 1];
  for (int k = beg; k < end; ++k) {
    int s = csr[k];
    uint4 u = *(const uint4*)&hh[(size_t)s * C + (size_t)q * 8];
    acc[0] += bf_lo(u.x); acc[1] += bf_hi(u.x);
    acc[2] += bf_lo(u.y); acc[3] += bf_hi(u.y);
    acc[4] += bf_lo(u.z); acc[5] += bf_hi(u.z);
    acc[6] += bf_lo(u.w); acc[7] += bf_hi(u.w);
  }
  const float dn = dinv[node];
  float4 b0 = *(const float4*)&bias[q * 8];
  float4 b1 = *(const float4*)&bias[q * 8 + 4];
  float r[8];
  r[0] = dn * acc[0] + b0.x; r[1] = dn * acc[1] + b0.y;
  r[2] = dn * acc[2] + b0.z; r[3] = dn * acc[3] + b0.w;
  r[4] = dn * acc[4] + b1.x; r[5] = dn * acc[5] + b1.y;
  r[6] = dn * acc[6] + b1.z; r[7] = dn * acc[7] + b1.w;
  if (RELU) {
#pragma unroll
    for (int j = 0; j < 8; ++j) r[j] = fmaxf(r[j], 0.0f);
  }
  if (OUTBF16) {
    ushort_t* out = (ushort_t*)outp;
    uint4 o;
    o.x = pack2(r[0], r[1]); o.y = pack2(r[2], r[3]);
    o.z = pack2(r[4], r[5]); o.w = pack2(r[6], r[7]);
    *(uint4*)&out[(size_t)node * C + (size_t)q * 8] = o;
  } else {
    float* out = (float*)outp;
    float4 o0, o1;
    o0.x = r[0]; o0.y = r[1]; o0.z = r[2]; o0.w = r[3];
    o1.x = r[4]; o1.y = r[5]; o1.z = r[6]; o1.w = r[7];
    *(float4*)&out[(size_t)node * C + (size_t)q * 8] = o0;
    *(float4*)&out[(size_t)node * C + (size_t)q * 8 + 4] = o1;
  }
}

extern "C" void kernel_launch(void* const* d_in, const int* in_sizes, int n_in,
                              void* d_out, int out_size, void* d_ws, size_t ws_size,
                              hipStream_t stream) {
  const float* x  = (const float*)d_in[0];
  const int*   ei = (const int*)d_in[1];
  const float* W1 = (const float*)d_in[2];
  const float* b1 = (const float*)d_in[3];
  const float* W2 = (const float*)d_in[4];
  const float* b2 = (const float*)d_in[5];
  float* out = (float*)d_out;

  const int n = in_sizes[0] / CIN;  // 50000
  const int e = in_sizes[1] / 2;    // 800000
  const int* src = ei;
  const int* dst = ei + e;

  // workspace layout (aligned 256B)
  size_t off = 0;
  auto alloc = [&](size_t bytes) {
    size_t o = off;
    off = (off + bytes + 255) & ~(size_t)255;
    return o;
  };
  char* ws = (char*)d_ws;
  int*      degi     = (int*)(ws + alloc((size_t)n * 4));
  int*      incl     = (int*)(ws + alloc((size_t)n * 4));
  int*      bsum     = (int*)(ws + alloc((size_t)SCAN_B * 4));
  int*      rowptr   = (int*)(ws + alloc((size_t)(n + 1) * 4));
  int*      counters = (int*)(ws + alloc((size_t)n * 4));
  int*      csr      = (int*)(ws + alloc((size_t)e * 4));
  float*    dinv     = (float*)(ws + alloc((size_t)n * 4));
  ushort_t* hhA      = (ushort_t*)(ws + alloc((size_t)n * CHID * 2));
  ushort_t* hhB      = (ushort_t*)(ws + alloc((size_t)n * CHID * 2));

  const int B = 256;
  const int nb = (n + SCAN_B - 1) / SCAN_B;

  // --- CSR build + dinv ---
  k_zero_int<<<(n + B - 1) / B, B, 0, stream>>>(degi, n);
  k_count_int<<<(e + B - 1) / B, B, 0, stream>>>(dst, degi, e);
  k_scan1<<<nb, SCAN_B, 0, stream>>>(degi, incl, bsum, n);
  k_scan2<<<1, SCAN_B, 0, stream>>>(bsum, nb);
  k_scan3<<<nb, SCAN_B, 0, stream>>>(incl, bsum, degi, rowptr, counters, dinv, n);
  k_fill_csr<<<(e + B - 1) / B, B, 0, stream>>>(src, dst, counters, csr, e);

  // --- layer 1: hhA = bf16(rowscale(x @ W1)) ---
  k_gemm_rs<CIN, CHID, 32, false><<<(n + 31) / 32, 256, 0, stream>>>(
      x, W1, dinv, hhA, n);
  // hhB = bf16(relu(dinv*(gather hhA) + b1))
  k_aggb<CHID, true, true><<<(n + 15) / 16, 256, 0, stream>>>(
      hhA, rowptr, csr, dinv, b1, hhB, n);

  // --- layer 2: hhA(reuse) = bf16(rowscale(hhB @ W2)) ---
  k_gemm_rs<CHID, COUT, 64, true><<<(n + 63) / 64, 256, 0, stream>>>(
      hhB, W2, dinv, hhA, n);
  // out = dinv*(gather hhA) + b2   (fp32 final)
  k_aggb<COUT, false, false><<<(n + 31) / 32, 256, 0, stream>>>(
      hhA, rowptr, csr, dinv, b2, out, n);
}

// Round 5
// 200.530 us; speedup vs baseline: 10.9985x; 1.2359x over previous
//
#include <hip/hip_runtime.h>

// GCN 2-layer: out = A_hat @ relu(A_hat @ (X W1) + b1) W2 + b2
// A_hat = D^-1/2 (A + I) D^-1/2.
//
// R5: MFMA bf16 GEMMs (16x16x32, fp32 accum). W pre-transposed+converted to
// bf16 Wt[c][k]; x converted fp32->bf16 during LDS staging. Fragment-major
// LDS layout -> all ds_read_b128 per-lane-linear (conflict-free).
// CSR-gather aggregation (bf16) unchanged from R4.

#define CIN 256
#define CHID 128
#define COUT 64
#define SCAN_B 256

typedef unsigned short ushort_t;
typedef unsigned int uint_t;
typedef __attribute__((ext_vector_type(8))) short short8;   // 8 bf16 (4 VGPR)
typedef __attribute__((ext_vector_type(4))) float f32x4;    // MFMA acc

__device__ inline ushort_t f2bf(float f) {  // RNE
  union { float f; uint_t u; } v; v.f = f;
  uint_t r = v.u + 0x7FFFu + ((v.u >> 16) & 1u);
  return (ushort_t)(r >> 16);
}
__device__ inline float bf2f(ushort_t u) {
  union { uint_t u; float f; } v; v.u = ((uint_t)u) << 16;
  return v.f;
}
__device__ inline float bf_lo(uint_t u) {
  union { uint_t u; float f; } v; v.u = u << 16;
  return v.f;
}
__device__ inline float bf_hi(uint_t u) {
  union { uint_t u; float f; } v; v.u = u & 0xFFFF0000u;
  return v.f;
}
__device__ inline uint_t pack2(float a, float b) {
  return (uint_t)f2bf(a) | ((uint_t)f2bf(b) << 16);
}

// ---------- small utils ----------
__global__ void k_zero_int(int* __restrict__ p, int n) {
  int i = blockIdx.x * blockDim.x + threadIdx.x;
  if (i < n) p[i] = 0;
}

__global__ void k_count_int(const int* __restrict__ dst, int* __restrict__ deg, int e) {
  int i = blockIdx.x * blockDim.x + threadIdx.x;
  if (i < e) atomicAdd(&deg[dst[i]], 1);
}

// Wt[c][k] = bf16(W[k][c]);  W is K x C row-major.
__global__ void k_wt(const float* __restrict__ W, ushort_t* __restrict__ Wt,
                     int K, int C) {
  int i = blockIdx.x * blockDim.x + threadIdx.x;  // i = c*K + k (k fastest)
  if (i >= K * C) return;
  int k = i % K, c = i / K;
  Wt[i] = f2bf(W[(size_t)k * C + c]);
}

// ---------- 3-kernel exclusive scan over deg ----------
__global__ void k_scan1(const int* __restrict__ deg, int* __restrict__ incl,
                        int* __restrict__ bsum, int n) {
  __shared__ int s[SCAN_B];
  int i = blockIdx.x * SCAN_B + threadIdx.x;
  int v = (i < n) ? deg[i] : 0;
  s[threadIdx.x] = v;
  __syncthreads();
  for (int off = 1; off < SCAN_B; off <<= 1) {
    int t = (threadIdx.x >= off) ? s[threadIdx.x - off] : 0;
    __syncthreads();
    s[threadIdx.x] += t;
    __syncthreads();
  }
  if (i < n) incl[i] = s[threadIdx.x];
  if (threadIdx.x == SCAN_B - 1) bsum[blockIdx.x] = s[SCAN_B - 1];
}

__global__ void k_scan2(int* __restrict__ bsum, int nb) {
  __shared__ int s[SCAN_B];
  int v = (threadIdx.x < nb) ? bsum[threadIdx.x] : 0;
  s[threadIdx.x] = v;
  __syncthreads();
  for (int off = 1; off < SCAN_B; off <<= 1) {
    int t = (threadIdx.x >= off) ? s[threadIdx.x - off] : 0;
    __syncthreads();
    s[threadIdx.x] += t;
    __syncthreads();
  }
  if (threadIdx.x < nb) bsum[threadIdx.x] = (threadIdx.x == 0) ? 0 : s[threadIdx.x - 1];
}

__global__ void k_scan3(const int* __restrict__ incl, const int* __restrict__ bsum,
                        const int* __restrict__ deg, int* __restrict__ rowptr,
                        int* __restrict__ counters, float* __restrict__ dinv, int n) {
  int i = blockIdx.x * SCAN_B + threadIdx.x;
  if (i >= n) return;
  int v = bsum[blockIdx.x] + incl[i];
  rowptr[i + 1] = v;
  counters[i] = v - deg[i];
  if (i == 0) rowptr[0] = 0;
  dinv[i] = rsqrtf((float)(deg[i] + 1));  // +1 self-loop
}

__global__ void k_fill_csr(const int* __restrict__ src, const int* __restrict__ dst,
                           int* __restrict__ counters, int* __restrict__ csr, int e) {
  int i = blockIdx.x * blockDim.x + threadIdx.x;
  if (i >= e) return;
  int slot = atomicAdd(&counters[dst[i]], 1);
  csr[slot] = src[i];
}

// ---------- MFMA GEMM: out[r][c] = bf16( dinv[r] * sum_k X[r][k] * Wt[c][k] )
// BM=128 rows/block, BK=32, 4 waves (wave w owns rows w*32..w*32+31, full N).
// Fragment-major LDS: subtile of 16 rows(cols) x 32 k -> 64 lanes x 8 bf16,
// lane = (r&15) + 16*(k>>3). Frag reads are lane-linear b128 (conflict-free).
template <int K, int BN, bool XBF16>
__global__ __launch_bounds__(256) void k_gemm_mfma(
    const void* __restrict__ Xv, const ushort_t* __restrict__ Wt,
    const float* __restrict__ dinv, ushort_t* __restrict__ out, int M) {
  constexpr int BM = 128, BK = 32;
  constexpr int NSUB = BN / 16;       // 8 (layer1) / 4 (layer2)
  constexpr int ASZ = BM * BK;        // 4096 bf16
  constexpr int BSZ = BK * BN;        // 4096 / 2048
  constexpr int NCH = K / BK;         // 8 / 4
  constexpr int AIT = ASZ / 8 / 256;  // 2
  constexpr int BIT = BSZ / 8 / 256;  // 2 / 1

  __shared__ ushort_t As[2][ASZ];
  __shared__ ushort_t Bs[2][BSZ];

  const int tid = threadIdx.x;
  const int lane = tid & 63;
  const int w = tid >> 6;
  const int row0 = blockIdx.x * BM;

  const float* Xf = (const float*)Xv;
  const ushort_t* Xb = (const ushort_t*)Xv;

  // prefetch registers
  float4 ar0[AIT], ar1[AIT];
  uint4 arb[AIT];
  uint4 brg[BIT];

  // A staging map: fi in [0,512): r = fi&127, kb = fi>>7 (k0 = kb*8).
  // Global: 64 consecutive lanes -> consecutive rows (stride K), 16B each.
  // LDS write: lanes 0-15 -> 256B contiguous => 2-way banks (free).
  auto load_A = [&](int kc) {
#pragma unroll
    for (int i = 0; i < AIT; ++i) {
      int fi = i * 256 + tid;
      int r = fi & 127, k0 = (fi >> 7) * 8;
      int gr = row0 + r;
      if (gr > M - 1) gr = M - 1;
      if (XBF16) {
        arb[i] = *(const uint4*)(Xb + (size_t)gr * K + kc + k0);
      } else {
        ar0[i] = *(const float4*)(Xf + (size_t)gr * K + kc + k0);
        ar1[i] = *(const float4*)(Xf + (size_t)gr * K + kc + k0 + 4);
      }
    }
#pragma unroll
    for (int i = 0; i < BIT; ++i) {
      int g = i * 256 + tid;
      int nf = g >> 6, l = g & 63;
      int c = nf * 16 + (l & 15), k0 = (l >> 4) * 8;
      brg[i] = *(const uint4*)(Wt + (size_t)c * K + kc + k0);
    }
  };

  auto write_lds = [&](int buf) {
#pragma unroll
    for (int i = 0; i < AIT; ++i) {
      int fi = i * 256 + tid;
      int r = fi & 127, kb = fi >> 7;
      int flat = (r >> 4) * 512 + ((r & 15) + 16 * kb) * 8;
      if (XBF16) {
        *(uint4*)&As[buf][flat] = arb[i];
      } else {
        uint4 p;
        p.x = pack2(ar0[i].x, ar0[i].y);
        p.y = pack2(ar0[i].z, ar0[i].w);
        p.z = pack2(ar1[i].x, ar1[i].y);
        p.w = pack2(ar1[i].z, ar1[i].w);
        *(uint4*)&As[buf][flat] = p;
      }
    }
#pragma unroll
    for (int i = 0; i < BIT; ++i) {
      int g = i * 256 + tid;
      int nf = g >> 6, l = g & 63;
      *(uint4*)&Bs[buf][nf * 512 + l * 8] = brg[i];  // lane-linear (free)
    }
  };

  f32x4 acc[2][NSUB];
#pragma unroll
  for (int mi = 0; mi < 2; ++mi)
#pragma unroll
    for (int ni = 0; ni < NSUB; ++ni)
      acc[mi][ni] = (f32x4){0.f, 0.f, 0.f, 0.f};

  load_A(0);
  write_lds(0);

#pragma unroll 1
  for (int ch = 0; ch < NCH; ++ch) {
    const int cur = ch & 1;
    __syncthreads();
    if (ch + 1 < NCH) load_A((ch + 1) * BK);

    short8 af[2];
#pragma unroll
    for (int mi = 0; mi < 2; ++mi)
      af[mi] = *(const short8*)&As[cur][(2 * w + mi) * 512 + lane * 8];
    short8 bf[NSUB];
#pragma unroll
    for (int ni = 0; ni < NSUB; ++ni)
      bf[ni] = *(const short8*)&Bs[cur][ni * 512 + lane * 8];

#pragma unroll
    for (int mi = 0; mi < 2; ++mi)
#pragma unroll
      for (int ni = 0; ni < NSUB; ++ni)
        acc[mi][ni] = __builtin_amdgcn_mfma_f32_16x16x32_bf16(
            af[mi], bf[ni], acc[mi][ni], 0, 0, 0);

    if (ch + 1 < NCH) write_lds(cur ^ 1);
  }

  // epilogue: D frag = col (lane&15), rows (lane>>4)*4 + v
  const int qrow = (lane >> 4) * 4;
  const int col16 = lane & 15;
#pragma unroll
  for (int mi = 0; mi < 2; ++mi) {
    int rbase = row0 + w * 32 + mi * 16 + qrow;
#pragma unroll
    for (int v = 0; v < 4; ++v) {
      int row = rbase + v;
      if (row < M) {
        float dn = dinv[row];
#pragma unroll
        for (int ni = 0; ni < NSUB; ++ni)
          out[(size_t)row * BN + ni * 16 + col16] = f2bf(dn * acc[mi][ni][v]);
      }
    }
  }
}

// ---------- bf16 gather aggregation ----------
// out[j] = act(dinv[j]*(hh[j] + sum_{e:dst=j} hh[src]) + b); hh bf16.
template <int C, bool RELU, bool OUTBF16>
__global__ __launch_bounds__(256) void k_aggb(
    const ushort_t* __restrict__ hh, const int* __restrict__ rowptr,
    const int* __restrict__ csr, const float* __restrict__ dinv,
    const float* __restrict__ bias, void* __restrict__ outp, int n) {
  constexpr int LPN = C / 8;
  constexpr int NPB = 256 / LPN;
  const int tid = threadIdx.x;
  const int node = blockIdx.x * NPB + tid / LPN;
  const int q = tid % LPN;
  if (node >= n) return;

  float acc[8];
  {
    uint4 u = *(const uint4*)&hh[(size_t)node * C + (size_t)q * 8];  // self-loop
    acc[0] = bf_lo(u.x); acc[1] = bf_hi(u.x);
    acc[2] = bf_lo(u.y); acc[3] = bf_hi(u.y);
    acc[4] = bf_lo(u.z); acc[5] = bf_hi(u.z);
    acc[6] = bf_lo(u.w); acc[7] = bf_hi(u.w);
  }
  const int beg = rowptr[node];
  const int end = rowptr[node + 1];
  for (int k = beg; k < end; ++k) {
    int s = csr[k];
    uint4 u = *(const uint4*)&hh[(size_t)s * C + (size_t)q * 8];
    acc[0] += bf_lo(u.x); acc[1] += bf_hi(u.x);
    acc[2] += bf_lo(u.y); acc[3] += bf_hi(u.y);
    acc[4] += bf_lo(u.z); acc[5] += bf_hi(u.z);
    acc[6] += bf_lo(u.w); acc[7] += bf_hi(u.w);
  }
  const float dn = dinv[node];
  float4 b0 = *(const float4*)&bias[q * 8];
  float4 b1 = *(const float4*)&bias[q * 8 + 4];
  float r[8];
  r[0] = dn * acc[0] + b0.x; r[1] = dn * acc[1] + b0.y;
  r[2] = dn * acc[2] + b0.z; r[3] = dn * acc[3] + b0.w;
  r[4] = dn * acc[4] + b1.x; r[5] = dn * acc[5] + b1.y;
  r[6] = dn * acc[6] + b1.z; r[7] = dn * acc[7] + b1.w;
  if (RELU) {
#pragma unroll
    for (int j = 0; j < 8; ++j) r[j] = fmaxf(r[j], 0.0f);
  }
  if (OUTBF16) {
    ushort_t* out = (ushort_t*)outp;
    uint4 o;
    o.x = pack2(r[0], r[1]); o.y = pack2(r[2], r[3]);
    o.z = pack2(r[4], r[5]); o.w = pack2(r[6], r[7]);
    *(uint4*)&out[(size_t)node * C + (size_t)q * 8] = o;
  } else {
    float* out = (float*)outp;
    float4 o0, o1;
    o0.x = r[0]; o0.y = r[1]; o0.z = r[2]; o0.w = r[3];
    o1.x = r[4]; o1.y = r[5]; o1.z = r[6]; o1.w = r[7];
    *(float4*)&out[(size_t)node * C + (size_t)q * 8] = o0;
    *(float4*)&out[(size_t)node * C + (size_t)q * 8 + 4] = o1;
  }
}

extern "C" void kernel_launch(void* const* d_in, const int* in_sizes, int n_in,
                              void* d_out, int out_size, void* d_ws, size_t ws_size,
                              hipStream_t stream) {
  const float* x  = (const float*)d_in[0];
  const int*   ei = (const int*)d_in[1];
  const float* W1 = (const float*)d_in[2];
  const float* b1 = (const float*)d_in[3];
  const float* W2 = (const float*)d_in[4];
  const float* b2 = (const float*)d_in[5];
  float* out = (float*)d_out;

  const int n = in_sizes[0] / CIN;  // 50000
  const int e = in_sizes[1] / 2;    // 800000
  const int* src = ei;
  const int* dst = ei + e;

  // workspace layout (aligned 256B)
  size_t off = 0;
  auto alloc = [&](size_t bytes) {
    size_t o = off;
    off = (off + bytes + 255) & ~(size_t)255;
    return o;
  };
  char* ws = (char*)d_ws;
  int*      degi     = (int*)(ws + alloc((size_t)n * 4));
  int*      incl     = (int*)(ws + alloc((size_t)n * 4));
  int*      bsum     = (int*)(ws + alloc((size_t)SCAN_B * 4));
  int*      rowptr   = (int*)(ws + alloc((size_t)(n + 1) * 4));
  int*      counters = (int*)(ws + alloc((size_t)n * 4));
  int*      csr      = (int*)(ws + alloc((size_t)e * 4));
  float*    dinv     = (float*)(ws + alloc((size_t)n * 4));
  ushort_t* wt1      = (ushort_t*)(ws + alloc((size_t)CIN * CHID * 2));
  ushort_t* wt2      = (ushort_t*)(ws + alloc((size_t)CHID * COUT * 2));
  ushort_t* hhA      = (ushort_t*)(ws + alloc((size_t)n * CHID * 2));
  ushort_t* hhB      = (ushort_t*)(ws + alloc((size_t)n * CHID * 2));

  const int B = 256;
  const int nb = (n + SCAN_B - 1) / SCAN_B;

  // --- W transpose+convert (tiny) ---
  k_wt<<<(CIN * CHID + B - 1) / B, B, 0, stream>>>(W1, wt1, CIN, CHID);
  k_wt<<<(CHID * COUT + B - 1) / B, B, 0, stream>>>(W2, wt2, CHID, COUT);

  // --- CSR build + dinv ---
  k_zero_int<<<(n + B - 1) / B, B, 0, stream>>>(degi, n);
  k_count_int<<<(e + B - 1) / B, B, 0, stream>>>(dst, degi, e);
  k_scan1<<<nb, SCAN_B, 0, stream>>>(degi, incl, bsum, n);
  k_scan2<<<1, SCAN_B, 0, stream>>>(bsum, nb);
  k_scan3<<<nb, SCAN_B, 0, stream>>>(incl, bsum, degi, rowptr, counters, dinv, n);
  k_fill_csr<<<(e + B - 1) / B, B, 0, stream>>>(src, dst, counters, csr, e);

  // --- layer 1 ---
  k_gemm_mfma<CIN, CHID, false><<<(n + 127) / 128, 256, 0, stream>>>(
      x, wt1, dinv, hhA, n);
  k_aggb<CHID, true, true><<<(n + 15) / 16, 256, 0, stream>>>(
      hhA, rowptr, csr, dinv, b1, hhB, n);

  // --- layer 2 ---
  k_gemm_mfma<CHID, COUT, true><<<(n + 127) / 128, 256, 0, stream>>>(
      hhB, wt2, dinv, hhA, n);
  k_aggb<COUT, false, false><<<(n + 31) / 32, 256, 0, stream>>>(
      hhA, rowptr, csr, dinv, b2, out, n);
}

// Round 6
// 155.138 us; speedup vs baseline: 14.2165x; 1.2926x over previous
//
#include <hip/hip_runtime.h>

// GCN 2-layer: out = A_hat @ relu(A_hat @ (X W1) + b1) W2 + b2
// A_hat = D^-1/2 (A + I) D^-1/2.
//
// R6: CSR build via two-level bucket counting sort (bucket = dst>>8).
// Replaces 1.6M device-scope atomics + random 4B scatters (52MB write-amp)
// with LDS histograms + region-local writes. deg/dinv/rowptr fall out of
// the per-bucket build. MFMA GEMMs + bf16 gather agg unchanged from R5.

#define CIN 256
#define CHID 128
#define COUT 64

typedef unsigned short ushort_t;
typedef unsigned int uint_t;
typedef __attribute__((ext_vector_type(8))) short short8;   // 8 bf16 (4 VGPR)
typedef __attribute__((ext_vector_type(4))) float f32x4;    // MFMA acc

__device__ inline ushort_t f2bf(float f) {  // RNE
  union { float f; uint_t u; } v; v.f = f;
  uint_t r = v.u + 0x7FFFu + ((v.u >> 16) & 1u);
  return (ushort_t)(r >> 16);
}
__device__ inline float bf2f(ushort_t u) {
  union { uint_t u; float f; } v; v.u = ((uint_t)u) << 16;
  return v.f;
}
__device__ inline float bf_lo(uint_t u) {
  union { uint_t u; float f; } v; v.u = u << 16;
  return v.f;
}
__device__ inline float bf_hi(uint_t u) {
  union { uint_t u; float f; } v; v.u = u & 0xFFFF0000u;
  return v.f;
}
__device__ inline uint_t pack2(float a, float b) {
  return (uint_t)f2bf(a) | ((uint_t)f2bf(b) << 16);
}

// ---------- small utils ----------
__global__ void k_zero_int(int* __restrict__ p, int n) {
  int i = blockIdx.x * blockDim.x + threadIdx.x;
  if (i < n) p[i] = 0;
}

// Wt[c][k] = bf16(W[k][c]);  W is K x C row-major.
__global__ void k_wt(const float* __restrict__ W, ushort_t* __restrict__ Wt,
                     int K, int C) {
  int i = blockIdx.x * blockDim.x + threadIdx.x;  // i = c*K + k (k fastest)
  if (i >= K * C) return;
  int k = i % K, c = i / K;
  Wt[i] = f2bf(W[(size_t)k * C + c]);
}

// ---------- bucket counting sort CSR build ----------
// bucket b = dst >> 8 (256 nodes per bucket, nbk = ceil(n/256) <= 256).

// pass 1: per-block LDS histogram -> global bucket counts
__global__ __launch_bounds__(256) void k_bhist(const int* __restrict__ dst,
                                               int* __restrict__ bcnt, int e, int nbk) {
  __shared__ int h[256];
  const int tid = threadIdx.x;
  h[tid] = 0;
  __syncthreads();
  const int per = (e + gridDim.x - 1) / gridDim.x;
  const int lo = blockIdx.x * per;
  const int hi = min(e, lo + per);
  for (int i = lo + tid; i < hi; i += 256) atomicAdd(&h[dst[i] >> 8], 1);
  __syncthreads();
  if (tid < nbk && h[tid]) atomicAdd(&bcnt[tid], h[tid]);
}

// pass 1b: exclusive scan of bucket counts (single block); bcur = copy.
__global__ __launch_bounds__(256) void k_bscan(const int* __restrict__ bcnt,
                                               int* __restrict__ bbase,
                                               int* __restrict__ bcur, int nbk, int e) {
  __shared__ int s[256];
  const int tid = threadIdx.x;
  int v = (tid < nbk) ? bcnt[tid] : 0;
  s[tid] = v;
  __syncthreads();
  for (int off = 1; off < 256; off <<= 1) {
    int t = (tid >= off) ? s[tid - off] : 0;
    __syncthreads();
    s[tid] += t;
    __syncthreads();
  }
  if (tid < nbk) {
    int excl = s[tid] - v;
    bbase[tid] = excl;
    bcur[tid] = excl;
  }
  if (tid == 0) bbase[nbk] = e;
}

// pass 2: scatter (dst,src) pairs into bucket-grouped regions.
// One global atomicAdd per (block,bucket) reserves a contiguous chunk.
__global__ __launch_bounds__(256) void k_bscatter(const int* __restrict__ src,
                                                  const int* __restrict__ dst,
                                                  int* __restrict__ bcur,
                                                  int2* __restrict__ pairs,
                                                  int e, int nbk) {
  __shared__ int h[256];
  __shared__ int base[256];
  const int tid = threadIdx.x;
  h[tid] = 0;
  __syncthreads();
  const int per = (e + gridDim.x - 1) / gridDim.x;
  const int lo = blockIdx.x * per;
  const int hi = min(e, lo + per);
  for (int i = lo + tid; i < hi; i += 256) atomicAdd(&h[dst[i] >> 8], 1);
  __syncthreads();
  int c = h[tid];
  base[tid] = (tid < nbk && c) ? atomicAdd(&bcur[tid], c) : 0;
  h[tid] = 0;
  __syncthreads();
  for (int i = lo + tid; i < hi; i += 256) {
    int d = dst[i];
    int bk = d >> 8;
    int off = atomicAdd(&h[bk], 1);
    int2 p;
    p.x = d;
    p.y = src[i];
    pairs[base[bk] + off] = p;
  }
}

// pass 3: one block per bucket. LDS histogram over 256 local nodes ->
// rowptr/dinv; LDS-cursor scatter of src into contiguous csr segment.
__global__ __launch_bounds__(256) void k_bbuild(const int2* __restrict__ pairs,
                                                const int* __restrict__ bbase,
                                                int* __restrict__ rowptr,
                                                float* __restrict__ dinv,
                                                int* __restrict__ csr, int n, int e) {
  __shared__ int h[256];
  __shared__ int s[256];
  const int tid = threadIdx.x;
  const int b = blockIdx.x;
  const int lo = bbase[b];
  const int hi = bbase[b + 1];
  h[tid] = 0;
  __syncthreads();
  for (int i = lo + tid; i < hi; i += 256) atomicAdd(&h[pairs[i].x & 255], 1);
  __syncthreads();
  const int deg = h[tid];
  s[tid] = deg;
  __syncthreads();
  for (int off = 1; off < 256; off <<= 1) {
    int t = (tid >= off) ? s[tid - off] : 0;
    __syncthreads();
    s[tid] += t;
    __syncthreads();
  }
  const int excl = s[tid] - deg;
  const int node = (b << 8) + tid;
  if (node < n) {
    rowptr[node] = lo + excl;
    dinv[node] = rsqrtf((float)(deg + 1));  // +1 self-loop
  }
  if (b == 0 && tid == 0) rowptr[n] = e;
  h[tid] = lo + excl;  // reuse as cursor
  __syncthreads();
  for (int i = lo + tid; i < hi; i += 256) {
    int2 p = pairs[i];
    int slot = atomicAdd(&h[p.x & 255], 1);
    csr[slot] = p.y;
  }
}

// ---------- MFMA GEMM: out[r][c] = bf16( dinv[r] * sum_k X[r][k] * Wt[c][k] )
// BM=128 rows/block, BK=32, 4 waves (wave w owns rows w*32..w*32+31, full N).
// Fragment-major LDS: subtile of 16 rows(cols) x 32 k -> 64 lanes x 8 bf16,
// lane = (r&15) + 16*(k>>3). Frag reads are lane-linear b128 (conflict-free).
template <int K, int BN, bool XBF16>
__global__ __launch_bounds__(256) void k_gemm_mfma(
    const void* __restrict__ Xv, const ushort_t* __restrict__ Wt,
    const float* __restrict__ dinv, ushort_t* __restrict__ out, int M) {
  constexpr int BM = 128, BK = 32;
  constexpr int NSUB = BN / 16;
  constexpr int ASZ = BM * BK;
  constexpr int BSZ = BK * BN;
  constexpr int NCH = K / BK;
  constexpr int AIT = ASZ / 8 / 256;
  constexpr int BIT = BSZ / 8 / 256;

  __shared__ ushort_t As[2][ASZ];
  __shared__ ushort_t Bs[2][BSZ];

  const int tid = threadIdx.x;
  const int lane = tid & 63;
  const int w = tid >> 6;
  const int row0 = blockIdx.x * BM;

  const float* Xf = (const float*)Xv;
  const ushort_t* Xb = (const ushort_t*)Xv;

  float4 ar0[AIT], ar1[AIT];
  uint4 arb[AIT];
  uint4 brg[BIT];

  auto load_A = [&](int kc) {
#pragma unroll
    for (int i = 0; i < AIT; ++i) {
      int fi = i * 256 + tid;
      int r = fi & 127, k0 = (fi >> 7) * 8;
      int gr = row0 + r;
      if (gr > M - 1) gr = M - 1;
      if (XBF16) {
        arb[i] = *(const uint4*)(Xb + (size_t)gr * K + kc + k0);
      } else {
        ar0[i] = *(const float4*)(Xf + (size_t)gr * K + kc + k0);
        ar1[i] = *(const float4*)(Xf + (size_t)gr * K + kc + k0 + 4);
      }
    }
#pragma unroll
    for (int i = 0; i < BIT; ++i) {
      int g = i * 256 + tid;
      int nf = g >> 6, l = g & 63;
      int c = nf * 16 + (l & 15), k0 = (l >> 4) * 8;
      brg[i] = *(const uint4*)(Wt + (size_t)c * K + kc + k0);
    }
  };

  auto write_lds = [&](int buf) {
#pragma unroll
    for (int i = 0; i < AIT; ++i) {
      int fi = i * 256 + tid;
      int r = fi & 127, kb = fi >> 7;
      int flat = (r >> 4) * 512 + ((r & 15) + 16 * kb) * 8;
      if (XBF16) {
        *(uint4*)&As[buf][flat] = arb[i];
      } else {
        uint4 p;
        p.x = pack2(ar0[i].x, ar0[i].y);
        p.y = pack2(ar0[i].z, ar0[i].w);
        p.z = pack2(ar1[i].x, ar1[i].y);
        p.w = pack2(ar1[i].z, ar1[i].w);
        *(uint4*)&As[buf][flat] = p;
      }
    }
#pragma unroll
    for (int i = 0; i < BIT; ++i) {
      int g = i * 256 + tid;
      int nf = g >> 6, l = g & 63;
      *(uint4*)&Bs[buf][nf * 512 + l * 8] = brg[i];
    }
  };

  f32x4 acc[2][NSUB];
#pragma unroll
  for (int mi = 0; mi < 2; ++mi)
#pragma unroll
    for (int ni = 0; ni < NSUB; ++ni)
      acc[mi][ni] = (f32x4){0.f, 0.f, 0.f, 0.f};

  load_A(0);
  write_lds(0);

#pragma unroll 1
  for (int ch = 0; ch < NCH; ++ch) {
    const int cur = ch & 1;
    __syncthreads();
    if (ch + 1 < NCH) load_A((ch + 1) * BK);

    short8 af[2];
#pragma unroll
    for (int mi = 0; mi < 2; ++mi)
      af[mi] = *(const short8*)&As[cur][(2 * w + mi) * 512 + lane * 8];
    short8 bf[NSUB];
#pragma unroll
    for (int ni = 0; ni < NSUB; ++ni)
      bf[ni] = *(const short8*)&Bs[cur][ni * 512 + lane * 8];

#pragma unroll
    for (int mi = 0; mi < 2; ++mi)
#pragma unroll
      for (int ni = 0; ni < NSUB; ++ni)
        acc[mi][ni] = __builtin_amdgcn_mfma_f32_16x16x32_bf16(
            af[mi], bf[ni], acc[mi][ni], 0, 0, 0);

    if (ch + 1 < NCH) write_lds(cur ^ 1);
  }

  const int qrow = (lane >> 4) * 4;
  const int col16 = lane & 15;
#pragma unroll
  for (int mi = 0; mi < 2; ++mi) {
    int rbase = row0 + w * 32 + mi * 16 + qrow;
#pragma unroll
    for (int v = 0; v < 4; ++v) {
      int row = rbase + v;
      if (row < M) {
        float dn = dinv[row];
#pragma unroll
        for (int ni = 0; ni < NSUB; ++ni)
          out[(size_t)row * BN + ni * 16 + col16] = f2bf(dn * acc[mi][ni][v]);
      }
    }
  }
}

// ---------- bf16 gather aggregation ----------
// out[j] = act(dinv[j]*(hh[j] + sum_{e:dst=j} hh[src]) + b); hh bf16.
template <int C, bool RELU, bool OUTBF16>
__global__ __launch_bounds__(256) void k_aggb(
    const ushort_t* __restrict__ hh, const int* __restrict__ rowptr,
    const int* __restrict__ csr, const float* __restrict__ dinv,
    const float* __restrict__ bias, void* __restrict__ outp, int n) {
  constexpr int LPN = C / 8;
  constexpr int NPB = 256 / LPN;
  const int tid = threadIdx.x;
  const int node = blockIdx.x * NPB + tid / LPN;
  const int q = tid % LPN;
  if (node >= n) return;

  float acc[8];
  {
    uint4 u = *(const uint4*)&hh[(size_t)node * C + (size_t)q * 8];  // self-loop
    acc[0] = bf_lo(u.x); acc[1] = bf_hi(u.x);
    acc[2] = bf_lo(u.y); acc[3] = bf_hi(u.y);
    acc[4] = bf_lo(u.z); acc[5] = bf_hi(u.z);
    acc[6] = bf_lo(u.w); acc[7] = bf_hi(u.w);
  }
  const int beg = rowptr[node];
  const int end = rowptr[node + 1];
  for (int k = beg; k < end; ++k) {
    int s = csr[k];
    uint4 u = *(const uint4*)&hh[(size_t)s * C + (size_t)q * 8];
    acc[0] += bf_lo(u.x); acc[1] += bf_hi(u.x);
    acc[2] += bf_lo(u.y); acc[3] += bf_hi(u.y);
    acc[4] += bf_lo(u.z); acc[5] += bf_hi(u.z);
    acc[6] += bf_lo(u.w); acc[7] += bf_hi(u.w);
  }
  const float dn = dinv[node];
  float4 b0 = *(const float4*)&bias[q * 8];
  float4 b1 = *(const float4*)&bias[q * 8 + 4];
  float r[8];
  r[0] = dn * acc[0] + b0.x; r[1] = dn * acc[1] + b0.y;
  r[2] = dn * acc[2] + b0.z; r[3] = dn * acc[3] + b0.w;
  r[4] = dn * acc[4] + b1.x; r[5] = dn * acc[5] + b1.y;
  r[6] = dn * acc[6] + b1.z; r[7] = dn * acc[7] + b1.w;
  if (RELU) {
#pragma unroll
    for (int j = 0; j < 8; ++j) r[j] = fmaxf(r[j], 0.0f);
  }
  if (OUTBF16) {
    ushort_t* out = (ushort_t*)outp;
    uint4 o;
    o.x = pack2(r[0], r[1]); o.y = pack2(r[2], r[3]);
    o.z = pack2(r[4], r[5]); o.w = pack2(r[6], r[7]);
    *(uint4*)&out[(size_t)node * C + (size_t)q * 8] = o;
  } else {
    float* out = (float*)outp;
    float4 o0, o1;
    o0.x = r[0]; o0.y = r[1]; o0.z = r[2]; o0.w = r[3];
    o1.x = r[4]; o1.y = r[5]; o1.z = r[6]; o1.w = r[7];
    *(float4*)&out[(size_t)node * C + (size_t)q * 8] = o0;
    *(float4*)&out[(size_t)node * C + (size_t)q * 8 + 4] = o1;
  }
}

extern "C" void kernel_launch(void* const* d_in, const int* in_sizes, int n_in,
                              void* d_out, int out_size, void* d_ws, size_t ws_size,
                              hipStream_t stream) {
  const float* x  = (const float*)d_in[0];
  const int*   ei = (const int*)d_in[1];
  const float* W1 = (const float*)d_in[2];
  const float* b1 = (const float*)d_in[3];
  const float* W2 = (const float*)d_in[4];
  const float* b2 = (const float*)d_in[5];
  float* out = (float*)d_out;

  const int n = in_sizes[0] / CIN;  // 50000
  const int e = in_sizes[1] / 2;    // 800000
  const int* src = ei;
  const int* dst = ei + e;
  const int nbk = (n + 255) >> 8;   // buckets (196)

  // workspace layout (aligned 256B)
  size_t off = 0;
  auto alloc = [&](size_t bytes) {
    size_t o = off;
    off = (off + bytes + 255) & ~(size_t)255;
    return o;
  };
  char* ws = (char*)d_ws;
  int*      bcnt   = (int*)(ws + alloc(256 * 4));
  int*      bbase  = (int*)(ws + alloc(257 * 4));
  int*      bcur   = (int*)(ws + alloc(256 * 4));
  int*      rowptr = (int*)(ws + alloc((size_t)(n + 1) * 4));
  float*    dinv   = (float*)(ws + alloc((size_t)n * 4));
  int*      csr    = (int*)(ws + alloc((size_t)e * 4));
  int2*     pairs  = (int2*)(ws + alloc((size_t)e * 8));
  ushort_t* wt1    = (ushort_t*)(ws + alloc((size_t)CIN * CHID * 2));
  ushort_t* wt2    = (ushort_t*)(ws + alloc((size_t)CHID * COUT * 2));
  ushort_t* hhA    = (ushort_t*)(ws + alloc((size_t)n * CHID * 2));
  ushort_t* hhB    = (ushort_t*)(ws + alloc((size_t)n * CHID * 2));

  const int B = 256;
  const int NSCAT = 512;

  // --- W transpose+convert (tiny) ---
  k_wt<<<(CIN * CHID + B - 1) / B, B, 0, stream>>>(W1, wt1, CIN, CHID);
  k_wt<<<(CHID * COUT + B - 1) / B, B, 0, stream>>>(W2, wt2, CHID, COUT);

  // --- CSR build (bucket counting sort) + dinv ---
  k_zero_int<<<1, 256, 0, stream>>>(bcnt, 256);
  k_bhist<<<NSCAT, 256, 0, stream>>>(dst, bcnt, e, nbk);
  k_bscan<<<1, 256, 0, stream>>>(bcnt, bbase, bcur, nbk, e);
  k_bscatter<<<NSCAT, 256, 0, stream>>>(src, dst, bcur, pairs, e, nbk);
  k_bbuild<<<nbk, 256, 0, stream>>>(pairs, bbase, rowptr, dinv, csr, n, e);

  // --- layer 1 ---
  k_gemm_mfma<CIN, CHID, false><<<(n + 127) / 128, 256, 0, stream>>>(
      x, wt1, dinv, hhA, n);
  k_aggb<CHID, true, true><<<(n + 15) / 16, 256, 0, stream>>>(
      hhA, rowptr, csr, dinv, b1, hhB, n);

  // --- layer 2 ---
  k_gemm_mfma<CHID, COUT, true><<<(n + 127) / 128, 256, 0, stream>>>(
      hhB, wt2, dinv, hhA, n);
  k_aggb<COUT, false, false><<<(n + 31) / 32, 256, 0, stream>>>(
      hhA, rowptr, csr, dinv, b2, out, n);
}